// Round 19
// baseline (134.986 us; speedup 1.0000x reference)
//
#include <hip/hip_runtime.h>
#include <hip/hip_bf16.h>

#define KBOX 256
#define CCH  256
#define NODES 196
#define OS 14
#define FTQ 3211264   // KBOX*196*64

typedef __attribute__((ext_vector_type(8))) short  bf16x8;
typedef __attribute__((ext_vector_type(8))) unsigned short u16x8;
typedef __attribute__((ext_vector_type(4))) float  f32x4;
typedef __attribute__((ext_vector_type(4))) short  s16x4;
typedef __attribute__((ext_vector_type(4))) int    i32x4;

__device__ __forceinline__ short f2bf(float x) {
  __hip_bfloat16 h = __float2bfloat16(x);
  return *reinterpret_cast<short*>(&h);
}
__device__ __forceinline__ float bf2f(unsigned short u) {
  unsigned int x = ((unsigned int)u) << 16;
  union { unsigned int i; float f; } c; c.i = x;
  return c.f;
}

#define MFMA16 __builtin_amdgcn_mfma_f32_16x16x32_bf16

// ---------------- prep: bn scale/shift, bf16 weight fragments ----------------
__global__ __launch_bounds__(256) void prep_kernel(
    const float* __restrict__ bn_sem_g, const float* __restrict__ bn_sem_b,
    const float* __restrict__ bn_sem_m, const float* __restrict__ bn_sem_v,
    const float* __restrict__ conv_sem_w, const float* __restrict__ conv_sem_b,
    const float* __restrict__ bn_fpn_g, const float* __restrict__ bn_fpn_b,
    const float* __restrict__ bn_fpn_m, const float* __restrict__ bn_fpn_v,
    const float* __restrict__ conv_fpn_w, const float* __restrict__ conv_fpn_b,
    const float* __restrict__ bn_aff_g, const float* __restrict__ bn_aff_b,
    const float* __restrict__ bn_aff_m, const float* __restrict__ bn_aff_v,
    const float* __restrict__ conv_aff_w, const float* __restrict__ g1w,
    const float* __restrict__ g2w,
    float* __restrict__ ss_sem, float* __restrict__ ss_fpn, float* __restrict__ ss_aff2,
    short* __restrict__ wfrag, short* __restrict__ wafrag, short* __restrict__ g1wf,
    short* __restrict__ g2wf)
{
  int gid = blockIdx.x * blockDim.x + threadIdx.x;
  int gsz = gridDim.x * blockDim.x;
  for (int c = gid; c < 256; c += gsz) {
    float s = bn_sem_g[c] * rsqrtf(bn_sem_v[c] + 1e-5f);
    ss_sem[c] = s; ss_sem[256 + c] = bn_sem_b[c] - bn_sem_m[c] * s;
    float s2 = bn_fpn_g[c] * rsqrtf(bn_fpn_v[c] + 1e-5f);
    ss_fpn[c] = s2; ss_fpn[256 + c] = bn_fpn_b[c] - bn_fpn_m[c] * s2;
  }
  for (int c = gid; c < 64; c += gsz) {
    float s = bn_aff_g[c] * rsqrtf(bn_aff_v[c] + 1e-5f);
    float sh = bn_aff_b[c] - bn_aff_m[c] * s;
    float bias = conv_sem_b[c] + conv_fpn_b[c];
    ss_aff2[c] = s; ss_aff2[64 + c] = bias * s + sh;
  }
  for (int idx = gid; idx < 144 * 4 * 64 * 8; idx += gsz) {
    int e = idx & 7, lane = (idx >> 3) & 63, nt = (idx >> 9) & 3, kstep = idx >> 11;
    int src = kstep / 72, rem = kstep % 72, icc = rem / 9, pos = rem % 9;
    int ky = pos / 3, kx = pos % 3;
    int oc = nt * 16 + (lane & 15);
    int ic = icc * 32 + (lane >> 4) * 8 + e;
    const float* w = src ? conv_fpn_w : conv_sem_w;
    wfrag[idx] = f2bf(w[((oc * 256 + ic) * 3 + ky) * 3 + kx]);
  }
  for (int idx = gid; idx < 2 * 13 * 64 * 8; idx += gsz) {
    int t = idx;
    int e = t & 7; t >>= 3;
    int lane = t & 63; t >>= 6;
    int nt = t % 13; int s = t / 13;
    int i = nt * 16 + (lane & 15);
    int ic = s * 32 + (lane >> 4) * 8 + e;
    wafrag[idx] = f2bf(i < NODES ? conv_aff_w[i * 64 + ic] : 0.f);
  }
  for (int idx = gid; idx < 8 * 64 * 8; idx += gsz) {
    int e = idx & 7, lane = (idx >> 3) & 63, ks = idx >> 9;
    int ic = ks * 32 + (lane >> 4) * 8 + e;
    int f = lane & 15;
    g1wf[idx] = f2bf(g1w[ic * 16 + f]);
  }
  for (int idx = gid; idx < 16 * 64 * 8; idx += gsz) {
    int e = idx & 7, lane = (idx >> 3) & 63, ct = idx >> 9;
    int kk = (lane >> 4) * 8 + e;
    int c = ct * 16 + (lane & 15);
    g2wf[idx] = f2bf(kk < 16 ? g2w[kk * 256 + c] : 0.f);
  }
}

// ---------------- NCHW f32 -> NHWC bf16 transpose (64x64 LDS tiles) ----------------
__global__ __launch_bounds__(256) void transpose_bf16_kernel(
    const float* __restrict__ in, unsigned short* __restrict__ out, int C, int HW)
{
  __shared__ float tile[64][65];
  int nh = (HW + 63) >> 6;
  int bi = blockIdx.x;
  int cb = bi % (C >> 6); bi /= (C >> 6);
  int hb = bi % nh; int b = bi / nh;
  int tx = threadIdx.x & 63, ty = threadIdx.x >> 6;
  const float* inb = in + (size_t)b * C * HW;
  unsigned short* outb = out + (size_t)b * HW * C;
  #pragma unroll
  for (int i = ty; i < 64; i += 4) {
    int c = cb * 64 + i, hw = hb * 64 + tx;
    tile[i][tx] = (hw < HW) ? inb[(size_t)c * HW + hw] : 0.f;
  }
  __syncthreads();
  int cp = threadIdx.x & 31;
  #pragma unroll
  for (int i = (int)(threadIdx.x >> 5); i < 64; i += 8) {
    int hw = hb * 64 + i;
    if (hw < HW) {
      ushort2 v;
      v.x = (unsigned short)f2bf(tile[cp * 2][i]);
      v.y = (unsigned short)f2bf(tile[cp * 2 + 1][i]);
      *(ushort2*)&outb[(size_t)hw * C + cb * 64 + cp * 2] = v;
    }
  }
}

// ---------------- roi_align from NHWC bf16 semantic, CHANNEL-SPLIT (r17-proven) ----------------
__global__ __launch_bounds__(512) void roi_align_kernel(
    const unsigned short* __restrict__ semt, const float* __restrict__ boxes,
    unsigned short* __restrict__ roi_sem)
{
  __shared__ unsigned short slab[5][29][128];   // 37,120 B -> 4 blocks/CU
  int bid = blockIdx.x;
  int ch = bid & 1, g = (bid >> 1) % 7, kb = bid / 14;
  int tid = threadIdx.x;
  const float* bx = boxes + kb * 5;
  int bb = (int)bx[0];
  float x1 = bx[1], y1 = bx[2];
  float xb = x1 + 0.5f, yv = y1 + 0.5f;
  int X0 = (int)floorf(xb); float fx = xb - (float)X0;
  int Y0 = (int)floorf(yv); float fy = yv - (float)Y0;
  const int c0 = ch * 128;
  const unsigned short* base = semt + (size_t)bb * 12544 * 256 + c0;
  int hw = tid >> 5, l32 = tid & 31;
  #pragma unroll
  for (int i = 0; i < 10; ++i) {
    int s = hw + i * 16;
    if (s < 145) {
      int r = s / 29, xi = s - r * 29;
      int yr = min(Y0 + 4 * g + r, 111);
      int xc = min(X0 + xi, 111);
      *(s16x4*)&slab[r][xi][l32 * 4] =
          *(const s16x4*)(base + ((size_t)yr * 112 + xc) * 256 + l32 * 4);
    }
  }
  __syncthreads();
  int c2 = tid & 63, grp = tid >> 6;
  int oyl = grp & 1, og = grp >> 1;
  int rb = oyl * 2;
  float w0 = 1.f - fy;
  unsigned short* op = roi_sem + (((size_t)kb * NODES) + (2 * g + oyl) * OS) * 256
                       + c0 + c2 * 2;
  #pragma unroll
  for (int oxs = 0; oxs < 4; ++oxs) {
    int ox = og * 4 + oxs;
    if (ox < 14) {
      float o0 = 0.f, o1 = 0.f;
      #pragma unroll
      for (int xi = 0; xi < 3; ++xi) {
        float xw = (xi == 0) ? (1.f - fx) : (xi == 1 ? 1.f : fx);
        const unsigned short* p0 = &slab[rb][2 * ox + xi][c2 * 2];
        const unsigned short* p1 = &slab[rb + 1][2 * ox + xi][c2 * 2];
        const unsigned short* p2 = &slab[rb + 2][2 * ox + xi][c2 * 2];
        o0 += xw * (w0 * bf2f(p0[0]) + bf2f(p1[0]) + fy * bf2f(p2[0]));
        o1 += xw * (w0 * bf2f(p0[1]) + bf2f(p1[1]) + fy * bf2f(p2[1]));
      }
      ushort2 v;
      v.x = (unsigned short)f2bf(o0 * 0.25f);
      v.y = (unsigned short)f2bf(o1 * 0.25f);
      *(ushort2*)(op + (size_t)ox * 256) = v;
    }
  }
}

// ---------------- bn_relu + 3x3 conv, ONE SOURCE per block, 4 FAT waves -> bf16 partial ----------------
// r13/r17-proven structure: block (k, src); 4 waves; wave owns M-tiles {w,w+4,w+8}
// (+t12 on w3) and all 4 N-tiles. 54.7 KB LDS -> 2 blocks/CU (8 waves/CU).
__global__ __launch_bounds__(256) void conv_ab_kernel(
    const unsigned short* __restrict__ roi_sem, const unsigned short* __restrict__ roif,
    const float* __restrict__ ss_sem, const float* __restrict__ ss_fpn,
    const short* __restrict__ wfrag, short* __restrict__ a_part)
{
  int bi = blockIdx.x;
  int k = bi >> 1, src = bi & 1;
  int tid = threadIdx.x;
  int wave = tid >> 6, lane = tid & 63;
  int l15 = lane & 15, lq = lane >> 4;
  __shared__ short lds_in[197][40];      // row 196 = zero pad row
  __shared__ short lds_wf[18432];
  __shared__ float lds_sc[256], lds_sh[256];

  {
    const float* ss = src ? ss_fpn : ss_sem;
    lds_sc[tid] = ss[tid]; lds_sh[tid] = ss[256 + tid];
  }
  if (tid < 40) lds_in[196][tid] = 0;

  int oyA[4], oxA[4], jA[4]; bool mvA[4];
  #pragma unroll
  for (int mi = 0; mi < 4; ++mi) {
    int mt = (mi < 3) ? (wave + mi * 4) : 12;
    mvA[mi] = (mi < 3) | (wave == 3);
    int j = mt * 16 + l15;
    jA[mi] = j;
    int oy = j / 14;
    oyA[mi] = oy; oxA[mi] = j - oy * 14;
  }

  u16x8 inv[4];
  i32x4 wv[9];
  const unsigned short* inp = (src ? roif : roi_sem) + (size_t)k * NODES * CCH;
  const short* wbase = wfrag + (size_t)src * 72 * 2048;

  f32x4 acc[4][4];   // [mi][n]
  #pragma unroll
  for (int i = 0; i < 4; ++i)
    #pragma unroll
    for (int j = 0; j < 4; ++j) acc[i][j] = f32x4{0.f, 0.f, 0.f, 0.f};

#define ISSUE_LOADS(P) do {                                                  \
    int icc_ = (P);                                                          \
    const unsigned short* in_ = inp + icc_ * 32;                             \
    _Pragma("unroll")                                                        \
    for (int i_ = 0; i_ < 3; ++i_) {                                         \
      int f_ = tid + i_ * 256;                                               \
      inv[i_] = *(const u16x8*)(in_ + (size_t)(f_ >> 2) * 256 + (f_ & 3) * 8); \
    }                                                                        \
    if (tid < 16) {                                                          \
      int f_ = 768 + tid;                                                    \
      inv[3] = *(const u16x8*)(in_ + (size_t)(f_ >> 2) * 256 + (f_ & 3) * 8); \
    }                                                                        \
    const i32x4* wsl_ = (const i32x4*)(wbase + (size_t)icc_ * 9 * 2048);     \
    _Pragma("unroll")                                                        \
    for (int i_ = 0; i_ < 9; ++i_) wv[i_] = wsl_[tid + i_ * 256];            \
  } while (0)

#define WRITE_STAGE(P) do {                                                  \
    int icc_ = (P);                                                          \
    _Pragma("unroll")                                                        \
    for (int i_ = 0; i_ < 3; ++i_) {                                         \
      int f_ = tid + i_ * 256;                                               \
      int j_ = f_ >> 2, cq_ = f_ & 3;                                        \
      bf16x8 pk_;                                                            \
      _Pragma("unroll")                                                      \
      for (int u_ = 0; u_ < 8; ++u_) {                                       \
        int c_ = icc_ * 32 + cq_ * 8 + u_;                                   \
        float x_ = bf2f(inv[i_][u_]) * lds_sc[c_] + lds_sh[c_];              \
        pk_[u_] = f2bf(fmaxf(x_, 0.f));                                      \
      }                                                                      \
      *(bf16x8*)&lds_in[j_][cq_ * 8] = pk_;                                  \
    }                                                                        \
    if (tid < 16) {                                                          \
      int f_ = 768 + tid; int j_ = f_ >> 2, cq_ = f_ & 3;                    \
      bf16x8 pk_;                                                            \
      _Pragma("unroll")                                                      \
      for (int u_ = 0; u_ < 8; ++u_) {                                       \
        int c_ = icc_ * 32 + cq_ * 8 + u_;                                   \
        float x_ = bf2f(inv[3][u_]) * lds_sc[c_] + lds_sh[c_];               \
        pk_[u_] = f2bf(fmaxf(x_, 0.f));                                      \
      }                                                                      \
      *(bf16x8*)&lds_in[j_][cq_ * 8] = pk_;                                  \
    }                                                                        \
    _Pragma("unroll")                                                        \
    for (int i_ = 0; i_ < 9; ++i_) ((i32x4*)lds_wf)[tid + i_ * 256] = wv[i_];\
  } while (0)

  ISSUE_LOADS(0);
  __syncthreads();
  WRITE_STAGE(0);

  for (int p = 0; p < 8; ++p) {
    __syncthreads();
    if (p < 7) ISSUE_LOADS(p + 1);
    #pragma unroll
    for (int pos = 0; pos < 9; ++pos) {
      int ky = pos / 3 - 1, kx = pos % 3 - 1;
      bf16x8 bfr[4];
      #pragma unroll
      for (int n = 0; n < 4; ++n)
        bfr[n] = *(const bf16x8*)&lds_wf[((pos * 4 + n) * 64 + lane) * 8];
      #pragma unroll
      for (int mi = 0; mi < 4; ++mi) {
        if (!mvA[mi]) continue;
        int ny = oyA[mi] + ky, nx = oxA[mi] + kx;
        bool v = (jA[mi] < 196) & ((unsigned)ny < 14u) & ((unsigned)nx < 14u);
        int np = v ? (ny * 14 + nx) : 196;
        bf16x8 afr = *(const bf16x8*)&lds_in[np][lq * 8];
        acc[mi][0] = MFMA16(afr, bfr[0], acc[mi][0], 0, 0, 0);
        acc[mi][1] = MFMA16(afr, bfr[1], acc[mi][1], 0, 0, 0);
        acc[mi][2] = MFMA16(afr, bfr[2], acc[mi][2], 0, 0, 0);
        acc[mi][3] = MFMA16(afr, bfr[3], acc[mi][3], 0, 0, 0);
      }
    }
    __syncthreads();
    if (p < 7) WRITE_STAGE(p + 1);
  }

  short* op = a_part + (size_t)src * FTQ;
  #pragma unroll
  for (int mi = 0; mi < 4; ++mi) {
    if (!mvA[mi]) continue;
    int mt = (mi < 3) ? (wave + mi * 4) : 12;
    #pragma unroll
    for (int n = 0; n < 4; ++n) {
      int oc = n * 16 + l15;
      #pragma unroll
      for (int r = 0; r < 4; ++r) {
        int j = mt * 16 + lq * 4 + r;
        if (j < NODES)
          op[((size_t)k * NODES + j) * 64 + oc] = f2bf(acc[mi][n][r]);
      }
    }
  }
#undef ISSUE_LOADS
#undef WRITE_STAGE
}

// ---------------- fused graph kernel (r13/r17: 2-slice combine, T14 prefetch, LDS-staged P7) ----------------
__global__ __launch_bounds__(1024, 1) void graph_kernel(
    const short* __restrict__ a_part, const float* __restrict__ ss_aff2,
    const short* __restrict__ wafrag,
    const float* __restrict__ aff_b, const short* __restrict__ g1wf,
    const float* __restrict__ g1b, const unsigned short* __restrict__ roif_bf,
    const short* __restrict__ g2wf, const float* __restrict__ g2b,
    const unsigned short* __restrict__ roi_sem, float* __restrict__ outp)
{
  __shared__ __align__(16) char smem[125840];
  const int tid = threadIdx.x, wave = tid >> 6, lane = tid & 63;
  const int l15 = lane & 15, lq = lane >> 4;
  const int k = blockIdx.x;

  char*  Ab   = smem;                       // [208][464 B] bf16 A^T; dead after P6 (P7: rst)
  short* wa   = (short*)(smem + 96512);
  short* yfr  = (short*)(smem + 96512);
  short* zsf  = (short*)(smem + 103680);
  float* dsl  = (float*)(smem + 123136);
  float* g1bl = (float*)(smem + 123968);
  float* g2bl = (float*)(smem + 124032);
  float* affb = (float*)(smem + 125056);

  const bool wv13 = (wave < 13);
  const int jr  = wave * 16 + l15;
  const int jrc = min(jr, 195);
  const i32x4 z4 = {};
  const unsigned short* rsmk = roi_sem + (size_t)k * 50176;

  // ---------- P0: combine 2 bf16 conv partials -> bn_aff relu bf16 A-frags; stage wa ----------
  bf16x8 af0 = {}, af1 = {};
  if (wv13) {
    float s0[8] = {0,0,0,0,0,0,0,0}, s1[8] = {0,0,0,0,0,0,0,0};
    #pragma unroll
    for (int sl = 0; sl < 2; ++sl) {
      const unsigned short* p = (const unsigned short*)a_part + (size_t)sl * FTQ
                                + ((size_t)k * NODES + jrc) * 64 + lq * 8;
      u16x8 v0 = *(const u16x8*)p;
      u16x8 v1 = *(const u16x8*)(p + 32);
      #pragma unroll
      for (int e = 0; e < 8; ++e) { s0[e] += bf2f(v0[e]); s1[e] += bf2f(v1[e]); }
    }
    #pragma unroll
    for (int e = 0; e < 8; ++e) {
      int oc0 = lq * 8 + e, oc1 = 32 + lq * 8 + e;
      af0[e] = f2bf(fmaxf(s0[e] * ss_aff2[oc0] + ss_aff2[64 + oc0], 0.f));
      af1[e] = f2bf(fmaxf(s1[e] * ss_aff2[oc1] + ss_aff2[64 + oc1], 0.f));
    }
  }
  {
    i32x4 w0 = ((const i32x4*)wafrag)[tid];
    i32x4 w1 = z4;
    if (tid < 640) w1 = ((const i32x4*)wafrag)[1024 + tid];
    if (tid < 832) {
      int r = tid >> 2, q = tid & 3;
      *(i32x4*)(Ab + r * 464 + 384 + q * 16) = z4;
    }
    if (tid < 196) affb[tid] = aff_b[tid];
    if (tid < 256) g2bl[tid] = g2b[tid];
    if (tid < 16)  g1bl[tid] = g1b[tid];
    ((i32x4*)wa)[tid] = w0;
    if (tid < 640) ((i32x4*)wa)[1024 + tid] = w1;
  }
  __syncthreads();

  // ---------- P1: aff 1x1 conv + sigmoid -> Ab; rowsum -> dsl ----------
  if (wv13) {
    float rsum[4] = {0.f, 0.f, 0.f, 0.f};
    #pragma unroll
    for (int n = 0; n < 13; ++n) {
      bf16x8 b0 = *(const bf16x8*)(wa + (n * 64 + lane) * 8);
      bf16x8 b1 = *(const bf16x8*)(wa + ((13 + n) * 64 + lane) * 8);
      f32x4 acc = {0.f, 0.f, 0.f, 0.f};
      acc = MFMA16(af0, b0, acc, 0, 0, 0);
      acc = MFMA16(af1, b1, acc, 0, 0, 0);
      int i = n * 16 + l15;
      bool iv = (i < 196);
      float bv = affb[iv ? i : 0];
      #pragma unroll
      for (int r = 0; r < 4; ++r) {
        float v = acc[r] + bv;
        float s = 1.f / (1.f + __expf(-v));
        if (iv) {
          rsum[r] += s;
          *(short*)(Ab + (wave * 16 + lq * 4 + r) * 464 + i * 2) = f2bf(s);
        }
      }
    }
    #pragma unroll
    for (int r = 0; r < 4; ++r) {
      float v = rsum[r];
      v += __shfl_xor(v, 1); v += __shfl_xor(v, 2);
      v += __shfl_xor(v, 4); v += __shfl_xor(v, 8);
      int j = wave * 16 + lq * 4 + r;
      if (l15 == 0 && j < 196) dsl[j] = rsqrtf(v);
    }
  }
  __syncthreads();

  // ---------- P2/P3: zero yfr+zsf; xw1 = X @ g1w (direct global frags) ----------
  *(i32x4*)(smem + 96512 + tid * 16) = z4;
  if (tid < 256) *(i32x4*)(smem + 96512 + (1024 + tid) * 16) = z4;
  f32x4 xacc = {0.f, 0.f, 0.f, 0.f};
  if (wv13) {
    const unsigned short* Xp = roif_bf + (size_t)k * 50176 + (size_t)jrc * 256 + lq * 8;
    #pragma unroll
    for (int ks = 0; ks < 8; ++ks) {
      bf16x8 xa = *(const bf16x8*)(Xp + ks * 32);
      bf16x8 xb = *(const bf16x8*)(g1wf + (ks * 64 + lane) * 8);
      xacc = MFMA16(xa, xb, xacc, 0, 0, 0);
    }
  }
  __syncthreads();

  // ---------- P4: y = dis*xw1 -> yfr B-frags ----------
  if (wv13) {
    #pragma unroll
    for (int r = 0; r < 4; ++r) {
      int i = wave * 16 + lq * 4 + r;
      if (i < 196) {
        float yv = dsl[i] * xacc[r];
        yfr[((i >> 5) * 64 + ((i >> 3) & 3) * 16 + l15) * 8 + (i & 7)] = f2bf(yv);
      }
    }
  }
  __syncthreads();

  // ---------- P5: agg1 ----------
  f32x4 g0 = {0.f, 0.f, 0.f, 0.f};
  if (wv13) {
    #pragma unroll
    for (int ks = 0; ks < 7; ++ks) {
      bf16x8 bb = *(const bf16x8*)(yfr + (ks * 64 + lane) * 8);
      bf16x8 a0 = *(const bf16x8*)(Ab + jr * 464 + ks * 64 + lq * 16);
      g0 = MFMA16(a0, bb, g0, 0, 0, 0);
    }
  }
  __syncthreads();
  if (wv13) {
    #pragma unroll
    for (int r = 0; r < 4; ++r) {
      int i = wave * 16 + lq * 4 + r;
      if (i < 196) {
        float d = dsl[i];
        float x1v = fmaxf(g0[r] * d + g1bl[l15], 0.f);
        yfr[((i >> 5) * 64 + ((i >> 3) & 3) * 16 + l15) * 8 + (i & 7)] = f2bf(d * x1v);
      }
    }
  }
  __syncthreads();

  // T14: issue roi_sem chunk-0 loads (rows 0..95) now; latency hides under P6 MFMAs.
  u16x8 pre0[3];
  #pragma unroll
  for (int it = 0; it < 3; ++it) {
    int v = tid + it * 1024;
    int row = v >> 5, cq = v & 31;
    pre0[it] = *(const u16x8*)(rsmk + (size_t)row * 256 + cq * 8);
  }

  // ---------- P6: agg2 -> zs (dis-scaled) -> zsf B-frags ----------
  if (wv13) {
    f32x4 z0 = {0.f, 0.f, 0.f, 0.f};
    #pragma unroll
    for (int ks = 0; ks < 7; ++ks) {
      bf16x8 bb = *(const bf16x8*)(yfr + (ks * 64 + lane) * 8);
      bf16x8 a0 = *(const bf16x8*)(Ab + jr * 464 + ks * 64 + lq * 16);
      z0 = MFMA16(a0, bb, z0, 0, 0, 0);
    }
    #pragma unroll
    for (int r = 0; r < 4; ++r) {
      int j = wave * 16 + lq * 4 + r;
      if (j < 196) {
        float zv = z0[r] * dsl[j];
        zsf[((j >> 4) * 64 + (l15 >> 3) * 16 + (j & 15)) * 8 + (l15 & 7)] = f2bf(zv);
      }
    }
  }
  __syncthreads();   // Ab dead from here; reuse as rst

  // ---------- P7: out[k,c,j] = mfma(w2_frag, zs_frag) + g2b[c] + roi_sem[k,j,c] ----------
  {
    bf16x8 wf = *(const bf16x8*)(g2wf + (wave * 64 + lane) * 8);
    float* op = outp + (size_t)k * 50176;
    unsigned short* rst = (unsigned short*)smem;
    const int c_ = wave * 16 + lq * 4;
    float gbv[4];
    #pragma unroll
    for (int r = 0; r < 4; ++r) gbv[r] = g2bl[c_ + r];
    #pragma unroll
    for (int it = 0; it < 3; ++it) {
      int v = tid + it * 1024;
      int row = v >> 5, cq = v & 31;
      *(u16x8*)&rst[row * 264 + cq * 8] = pre0[it];
    }
    __syncthreads();
    u16x8 pre1[4];
    #pragma unroll
    for (int it = 0; it < 4; ++it) {
      int v = tid + it * 1024;
      if (v < 3200) {
        int row = v >> 5, cq = v & 31;
        pre1[it] = *(const u16x8*)(rsmk + (size_t)(96 + row) * 256 + cq * 8);
      }
    }
    #pragma unroll
    for (int jt = 0; jt < 6; ++jt) {
      bf16x8 zb = *(const bf16x8*)(zsf + (jt * 64 + lane) * 8);
      f32x4 d = {0.f, 0.f, 0.f, 0.f};
      d = MFMA16(wf, zb, d, 0, 0, 0);
      int j = jt * 16 + l15;
      const unsigned short* rr = rst + j * 264 + c_;
      unsigned int p01 = *(const unsigned int*)rr;
      unsigned int p23 = *(const unsigned int*)(rr + 2);
      op[(size_t)(c_ + 0) * 196 + j] = d[0] + gbv[0] + bf2f((unsigned short)(p01 & 0xffff));
      op[(size_t)(c_ + 1) * 196 + j] = d[1] + gbv[1] + bf2f((unsigned short)(p01 >> 16));
      op[(size_t)(c_ + 2) * 196 + j] = d[2] + gbv[2] + bf2f((unsigned short)(p23 & 0xffff));
      op[(size_t)(c_ + 3) * 196 + j] = d[3] + gbv[3] + bf2f((unsigned short)(p23 >> 16));
    }
    __syncthreads();
    #pragma unroll
    for (int it = 0; it < 4; ++it) {
      int v = tid + it * 1024;
      if (v < 3200) {
        int row = v >> 5, cq = v & 31;
        *(u16x8*)&rst[row * 264 + cq * 8] = pre1[it];
      }
    }
    __syncthreads();
    #pragma unroll
    for (int jt = 6; jt < 13; ++jt) {
      bf16x8 zb = *(const bf16x8*)(zsf + (jt * 64 + lane) * 8);
      f32x4 d = {0.f, 0.f, 0.f, 0.f};
      d = MFMA16(wf, zb, d, 0, 0, 0);
      int j = jt * 16 + l15;
      if (j < 196) {
        const unsigned short* rr = rst + (j - 96) * 264 + c_;
        unsigned int p01 = *(const unsigned int*)rr;
        unsigned int p23 = *(const unsigned int*)(rr + 2);
        op[(size_t)(c_ + 0) * 196 + j] = d[0] + gbv[0] + bf2f((unsigned short)(p01 & 0xffff));
        op[(size_t)(c_ + 1) * 196 + j] = d[1] + gbv[1] + bf2f((unsigned short)(p01 >> 16));
        op[(size_t)(c_ + 2) * 196 + j] = d[2] + gbv[2] + bf2f((unsigned short)(p23 & 0xffff));
        op[(size_t)(c_ + 3) * 196 + j] = d[3] + gbv[3] + bf2f((unsigned short)(p23 >> 16));
      }
    }
  }
}

extern "C" void kernel_launch(void* const* d_in, const int* in_sizes, int n_in,
                              void* d_out, int out_size, void* d_ws, size_t ws_size,
                              hipStream_t stream) {
  const float* roi_feature = (const float*)d_in[0];
  const float* semantic    = (const float*)d_in[1];
  const float* boxes       = (const float*)d_in[2];
  const float* bn_sem_g = (const float*)d_in[3];
  const float* bn_sem_b = (const float*)d_in[4];
  const float* bn_sem_m = (const float*)d_in[5];
  const float* bn_sem_v = (const float*)d_in[6];
  const float* conv_sem_w = (const float*)d_in[7];
  const float* conv_sem_b = (const float*)d_in[8];
  const float* bn_fpn_g = (const float*)d_in[9];
  const float* bn_fpn_b = (const float*)d_in[10];
  const float* bn_fpn_m = (const float*)d_in[11];
  const float* bn_fpn_v = (const float*)d_in[12];
  const float* conv_fpn_w = (const float*)d_in[13];
  const float* conv_fpn_b = (const float*)d_in[14];
  const float* bn_aff_g = (const float*)d_in[15];
  const float* bn_aff_b = (const float*)d_in[16];
  const float* bn_aff_m = (const float*)d_in[17];
  const float* bn_aff_v = (const float*)d_in[18];
  const float* conv_aff_w = (const float*)d_in[19];
  const float* conv_aff_b = (const float*)d_in[20];
  const float* gcn1_w = (const float*)d_in[21];
  const float* gcn1_b = (const float*)d_in[22];
  const float* gcn2_w = (const float*)d_in[23];
  const float* gcn2_b = (const float*)d_in[24];

  const size_t FT = (size_t)KBOX * NODES * CCH;       // 12,845,056 elements
  unsigned short* ws16      = (unsigned short*)d_ws;
  unsigned short* semt_bf   = ws16;                    // FT shorts
  unsigned short* roif_bf   = semt_bf + FT;
  unsigned short* roi_sem_b = roif_bf + FT;
  short*          a_part    = (short*)(roi_sem_b + FT);          // 2*FTQ bf16
  float*          ss_sem    = (float*)(a_part + 2 * (size_t)FTQ); // 512
  float*          ss_fpn    = ss_sem + 512;                      // 512
  float*          ss_aff2   = ss_fpn + 512;                      // 128
  short*          wfrag     = (short*)(ss_aff2 + 128);           // 294,912
  short*          wafrag    = wfrag + 294912;                    // 13,312
  short*          g1wf      = wafrag + 13312;                    // 4,096
  short*          g2wf      = g1wf + 4096;                       // 8,192

  prep_kernel<<<256, 256, 0, stream>>>(
      bn_sem_g, bn_sem_b, bn_sem_m, bn_sem_v, conv_sem_w, conv_sem_b,
      bn_fpn_g, bn_fpn_b, bn_fpn_m, bn_fpn_v, conv_fpn_w, conv_fpn_b,
      bn_aff_g, bn_aff_b, bn_aff_m, bn_aff_v, conv_aff_w, gcn1_w, gcn2_w,
      ss_sem, ss_fpn, ss_aff2, wfrag, wafrag, g1wf, g2wf);

  transpose_bf16_kernel<<<4 * 4 * 256, 256, 0, stream>>>(roi_feature, roif_bf, 256, 196);
  transpose_bf16_kernel<<<4 * 196 * 4, 256, 0, stream>>>(semantic, semt_bf, 256, 12544);
  roi_align_kernel<<<KBOX * 14, 512, 0, stream>>>(semt_bf, boxes, roi_sem_b);
  conv_ab_kernel<<<KBOX * 2, 256, 0, stream>>>(roi_sem_b, roif_bf, ss_sem, ss_fpn, wfrag, a_part);
  graph_kernel<<<KBOX, 1024, 0, stream>>>(a_part, ss_aff2, wafrag, conv_aff_b, g1wf, gcn1_b,
                                          roif_bf, g2wf, gcn2_b, roi_sem_b, (float*)d_out);
}

// Round 20
// 132.541 us; speedup vs baseline: 1.0185x; 1.0185x over previous
//
#include <hip/hip_runtime.h>
#include <hip/hip_bf16.h>

#define KBOX 256
#define CCH  256
#define NODES 196
#define OS 14
#define FTQ 3211264   // KBOX*196*64

typedef __attribute__((ext_vector_type(8))) short  bf16x8;
typedef __attribute__((ext_vector_type(8))) unsigned short u16x8;
typedef __attribute__((ext_vector_type(4))) float  f32x4;
typedef __attribute__((ext_vector_type(4))) short  s16x4;
typedef __attribute__((ext_vector_type(4))) int    i32x4;

__device__ __forceinline__ short f2bf(float x) {
  __hip_bfloat16 h = __float2bfloat16(x);
  return *reinterpret_cast<short*>(&h);
}
__device__ __forceinline__ float bf2f(unsigned short u) {
  unsigned int x = ((unsigned int)u) << 16;
  union { unsigned int i; float f; } c; c.i = x;
  return c.f;
}

#define MFMA16 __builtin_amdgcn_mfma_f32_16x16x32_bf16

// ---------------- prep: bn scale/shift, bf16 weight fragments ----------------
__global__ __launch_bounds__(256) void prep_kernel(
    const float* __restrict__ bn_sem_g, const float* __restrict__ bn_sem_b,
    const float* __restrict__ bn_sem_m, const float* __restrict__ bn_sem_v,
    const float* __restrict__ conv_sem_w, const float* __restrict__ conv_sem_b,
    const float* __restrict__ bn_fpn_g, const float* __restrict__ bn_fpn_b,
    const float* __restrict__ bn_fpn_m, const float* __restrict__ bn_fpn_v,
    const float* __restrict__ conv_fpn_w, const float* __restrict__ conv_fpn_b,
    const float* __restrict__ bn_aff_g, const float* __restrict__ bn_aff_b,
    const float* __restrict__ bn_aff_m, const float* __restrict__ bn_aff_v,
    const float* __restrict__ conv_aff_w, const float* __restrict__ g1w,
    const float* __restrict__ g2w,
    float* __restrict__ ss_sem, float* __restrict__ ss_fpn, float* __restrict__ ss_aff2,
    short* __restrict__ wfrag, short* __restrict__ wafrag, short* __restrict__ g1wf,
    short* __restrict__ g2wf)
{
  int gid = blockIdx.x * blockDim.x + threadIdx.x;
  int gsz = gridDim.x * blockDim.x;
  for (int c = gid; c < 256; c += gsz) {
    float s = bn_sem_g[c] * rsqrtf(bn_sem_v[c] + 1e-5f);
    ss_sem[c] = s; ss_sem[256 + c] = bn_sem_b[c] - bn_sem_m[c] * s;
    float s2 = bn_fpn_g[c] * rsqrtf(bn_fpn_v[c] + 1e-5f);
    ss_fpn[c] = s2; ss_fpn[256 + c] = bn_fpn_b[c] - bn_fpn_m[c] * s2;
  }
  for (int c = gid; c < 64; c += gsz) {
    float s = bn_aff_g[c] * rsqrtf(bn_aff_v[c] + 1e-5f);
    float sh = bn_aff_b[c] - bn_aff_m[c] * s;
    float bias = conv_sem_b[c] + conv_fpn_b[c];
    ss_aff2[c] = s; ss_aff2[64 + c] = bias * s + sh;
  }
  for (int idx = gid; idx < 144 * 4 * 64 * 8; idx += gsz) {
    int e = idx & 7, lane = (idx >> 3) & 63, nt = (idx >> 9) & 3, kstep = idx >> 11;
    int src = kstep / 72, rem = kstep % 72, icc = rem / 9, pos = rem % 9;
    int ky = pos / 3, kx = pos % 3;
    int oc = nt * 16 + (lane & 15);
    int ic = icc * 32 + (lane >> 4) * 8 + e;
    const float* w = src ? conv_fpn_w : conv_sem_w;
    wfrag[idx] = f2bf(w[((oc * 256 + ic) * 3 + ky) * 3 + kx]);
  }
  for (int idx = gid; idx < 2 * 13 * 64 * 8; idx += gsz) {
    int t = idx;
    int e = t & 7; t >>= 3;
    int lane = t & 63; t >>= 6;
    int nt = t % 13; int s = t / 13;
    int i = nt * 16 + (lane & 15);
    int ic = s * 32 + (lane >> 4) * 8 + e;
    wafrag[idx] = f2bf(i < NODES ? conv_aff_w[i * 64 + ic] : 0.f);
  }
  for (int idx = gid; idx < 8 * 64 * 8; idx += gsz) {
    int e = idx & 7, lane = (idx >> 3) & 63, ks = idx >> 9;
    int ic = ks * 32 + (lane >> 4) * 8 + e;
    int f = lane & 15;
    g1wf[idx] = f2bf(g1w[ic * 16 + f]);
  }
  for (int idx = gid; idx < 16 * 64 * 8; idx += gsz) {
    int e = idx & 7, lane = (idx >> 3) & 63, ct = idx >> 9;
    int kk = (lane >> 4) * 8 + e;
    int c = ct * 16 + (lane & 15);
    g2wf[idx] = f2bf(kk < 16 ? g2w[kk * 256 + c] : 0.f);
  }
}

// ---------------- NCHW f32 -> NHWC bf16 transpose (64x64 LDS tiles) ----------------
__global__ __launch_bounds__(256) void transpose_bf16_kernel(
    const float* __restrict__ in, unsigned short* __restrict__ out, int C, int HW)
{
  __shared__ float tile[64][65];
  int nh = (HW + 63) >> 6;
  int bi = blockIdx.x;
  int cb = bi % (C >> 6); bi /= (C >> 6);
  int hb = bi % nh; int b = bi / nh;
  int tx = threadIdx.x & 63, ty = threadIdx.x >> 6;
  const float* inb = in + (size_t)b * C * HW;
  unsigned short* outb = out + (size_t)b * HW * C;
  #pragma unroll
  for (int i = ty; i < 64; i += 4) {
    int c = cb * 64 + i, hw = hb * 64 + tx;
    tile[i][tx] = (hw < HW) ? inb[(size_t)c * HW + hw] : 0.f;
  }
  __syncthreads();
  int cp = threadIdx.x & 31;
  #pragma unroll
  for (int i = (int)(threadIdx.x >> 5); i < 64; i += 8) {
    int hw = hb * 64 + i;
    if (hw < HW) {
      ushort2 v;
      v.x = (unsigned short)f2bf(tile[cp * 2][i]);
      v.y = (unsigned short)f2bf(tile[cp * 2 + 1][i]);
      *(ushort2*)&outb[(size_t)hw * C + cb * 64 + cp * 2] = v;
    }
  }
}

// ---------------- roi_align from NHWC bf16 semantic, CHANNEL-SPLIT (r17-proven) ----------------
__global__ __launch_bounds__(512) void roi_align_kernel(
    const unsigned short* __restrict__ semt, const float* __restrict__ boxes,
    unsigned short* __restrict__ roi_sem)
{
  __shared__ unsigned short slab[5][29][128];   // 37,120 B -> 4 blocks/CU
  int bid = blockIdx.x;
  int ch = bid & 1, g = (bid >> 1) % 7, kb = bid / 14;
  int tid = threadIdx.x;
  const float* bx = boxes + kb * 5;
  int bb = (int)bx[0];
  float x1 = bx[1], y1 = bx[2];
  float xb = x1 + 0.5f, yv = y1 + 0.5f;
  int X0 = (int)floorf(xb); float fx = xb - (float)X0;
  int Y0 = (int)floorf(yv); float fy = yv - (float)Y0;
  const int c0 = ch * 128;
  const unsigned short* base = semt + (size_t)bb * 12544 * 256 + c0;
  int hw = tid >> 5, l32 = tid & 31;
  #pragma unroll
  for (int i = 0; i < 10; ++i) {
    int s = hw + i * 16;
    if (s < 145) {
      int r = s / 29, xi = s - r * 29;
      int yr = min(Y0 + 4 * g + r, 111);
      int xc = min(X0 + xi, 111);
      *(s16x4*)&slab[r][xi][l32 * 4] =
          *(const s16x4*)(base + ((size_t)yr * 112 + xc) * 256 + l32 * 4);
    }
  }
  __syncthreads();
  int c2 = tid & 63, grp = tid >> 6;
  int oyl = grp & 1, og = grp >> 1;
  int rb = oyl * 2;
  float w0 = 1.f - fy;
  unsigned short* op = roi_sem + (((size_t)kb * NODES) + (2 * g + oyl) * OS) * 256
                       + c0 + c2 * 2;
  #pragma unroll
  for (int oxs = 0; oxs < 4; ++oxs) {
    int ox = og * 4 + oxs;
    if (ox < 14) {
      float o0 = 0.f, o1 = 0.f;
      #pragma unroll
      for (int xi = 0; xi < 3; ++xi) {
        float xw = (xi == 0) ? (1.f - fx) : (xi == 1 ? 1.f : fx);
        const unsigned short* p0 = &slab[rb][2 * ox + xi][c2 * 2];
        const unsigned short* p1 = &slab[rb + 1][2 * ox + xi][c2 * 2];
        const unsigned short* p2 = &slab[rb + 2][2 * ox + xi][c2 * 2];
        o0 += xw * (w0 * bf2f(p0[0]) + bf2f(p1[0]) + fy * bf2f(p2[0]));
        o1 += xw * (w0 * bf2f(p0[1]) + bf2f(p1[1]) + fy * bf2f(p2[1]));
      }
      ushort2 v;
      v.x = (unsigned short)f2bf(o0 * 0.25f);
      v.y = (unsigned short)f2bf(o1 * 0.25f);
      *(ushort2*)(op + (size_t)ox * 256) = v;
    }
  }
}

// ---------------- bn_relu + 3x3 conv, ONE SOURCE per block, 4 FAT waves -> bf16 partial ----------------
// r17 structure + WEIGHT STAGING via global_load_lds DMA: removes 9 ds_write_b128/thread
// and 36 VGPRs per phase (wv[] eliminated). DMA issued after the post-MFMA barrier into
// the (now read-free) lds_wf; drained by the loop-top barrier's implicit vmcnt(0).
__global__ __launch_bounds__(256) void conv_ab_kernel(
    const unsigned short* __restrict__ roi_sem, const unsigned short* __restrict__ roif,
    const float* __restrict__ ss_sem, const float* __restrict__ ss_fpn,
    const short* __restrict__ wfrag, short* __restrict__ a_part)
{
  int bi = blockIdx.x;
  int k = bi >> 1, src = bi & 1;
  int tid = threadIdx.x;
  int wave = tid >> 6, lane = tid & 63;
  int l15 = lane & 15, lq = lane >> 4;
  __shared__ short lds_in[197][40];      // row 196 = zero pad row
  __shared__ short lds_wf[18432];
  __shared__ float lds_sc[256], lds_sh[256];

  {
    const float* ss = src ? ss_fpn : ss_sem;
    lds_sc[tid] = ss[tid]; lds_sh[tid] = ss[256 + tid];
  }
  if (tid < 40) lds_in[196][tid] = 0;

  int oyA[4], oxA[4], jA[4]; bool mvA[4];
  #pragma unroll
  for (int mi = 0; mi < 4; ++mi) {
    int mt = (mi < 3) ? (wave + mi * 4) : 12;
    mvA[mi] = (mi < 3) | (wave == 3);
    int j = mt * 16 + l15;
    jA[mi] = j;
    int oy = j / 14;
    oyA[mi] = oy; oxA[mi] = j - oy * 14;
  }

  u16x8 inv[4];
  const unsigned short* inp = (src ? roif : roi_sem) + (size_t)k * NODES * CCH;
  const short* wbase = wfrag + (size_t)src * 72 * 2048;

  f32x4 acc[4][4];   // [mi][n]
  #pragma unroll
  for (int i = 0; i < 4; ++i)
    #pragma unroll
    for (int j = 0; j < 4; ++j) acc[i][j] = f32x4{0.f, 0.f, 0.f, 0.f};

#define ISSUE_LOADS(P) do {                                                  \
    int icc_ = (P);                                                          \
    const unsigned short* in_ = inp + icc_ * 32;                             \
    _Pragma("unroll")                                                        \
    for (int i_ = 0; i_ < 3; ++i_) {                                         \
      int f_ = tid + i_ * 256;                                               \
      inv[i_] = *(const u16x8*)(in_ + (size_t)(f_ >> 2) * 256 + (f_ & 3) * 8); \
    }                                                                        \
    if (tid < 16) {                                                          \
      int f_ = 768 + tid;                                                    \
      inv[3] = *(const u16x8*)(in_ + (size_t)(f_ >> 2) * 256 + (f_ & 3) * 8); \
    }                                                                        \
  } while (0)

#define ISSUE_WDMA(P) do {                                                   \
    int icc_ = (P);                                                          \
    const char* wsl_ = (const char*)(wbase + (size_t)icc_ * 18432);          \
    _Pragma("unroll")                                                        \
    for (int i_ = 0; i_ < 9; ++i_) {                                         \
      int off_ = (i_ * 4 + wave) * 1024;                                     \
      __builtin_amdgcn_global_load_lds(                                      \
          (const __attribute__((address_space(1))) unsigned int*)(wsl_ + off_ + lane * 16), \
          (__attribute__((address_space(3))) unsigned int*)((char*)lds_wf + off_),          \
          16, 0, 0);                                                         \
    }                                                                        \
  } while (0)

#define WRITE_STAGE(P) do {                                                  \
    int icc_ = (P);                                                          \
    _Pragma("unroll")                                                        \
    for (int i_ = 0; i_ < 3; ++i_) {                                         \
      int f_ = tid + i_ * 256;                                               \
      int j_ = f_ >> 2, cq_ = f_ & 3;                                        \
      bf16x8 pk_;                                                            \
      _Pragma("unroll")                                                      \
      for (int u_ = 0; u_ < 8; ++u_) {                                       \
        int c_ = icc_ * 32 + cq_ * 8 + u_;                                   \
        float x_ = bf2f(inv[i_][u_]) * lds_sc[c_] + lds_sh[c_];              \
        pk_[u_] = f2bf(fmaxf(x_, 0.f));                                      \
      }                                                                      \
      *(bf16x8*)&lds_in[j_][cq_ * 8] = pk_;                                  \
    }                                                                        \
    if (tid < 16) {                                                          \
      int f_ = 768 + tid; int j_ = f_ >> 2, cq_ = f_ & 3;                    \
      bf16x8 pk_;                                                            \
      _Pragma("unroll")                                                      \
      for (int u_ = 0; u_ < 8; ++u_) {                                       \
        int c_ = icc_ * 32 + cq_ * 8 + u_;                                   \
        float x_ = bf2f(inv[3][u_]) * lds_sc[c_] + lds_sh[c_];               \
        pk_[u_] = f2bf(fmaxf(x_, 0.f));                                      \
      }                                                                      \
      *(bf16x8*)&lds_in[j_][cq_ * 8] = pk_;                                  \
    }                                                                        \
  } while (0)

  ISSUE_LOADS(0);
  ISSUE_WDMA(0);
  __syncthreads();            // tables + zero row visible; loads(0)+WDMA(0) drained
  WRITE_STAGE(0);

  for (int p = 0; p < 8; ++p) {
    __syncthreads();          // stage p fully visible (incl. weight DMA)
    if (p < 7) ISSUE_LOADS(p + 1);
    #pragma unroll
    for (int pos = 0; pos < 9; ++pos) {
      int ky = pos / 3 - 1, kx = pos % 3 - 1;
      bf16x8 bfr[4];
      #pragma unroll
      for (int n = 0; n < 4; ++n)
        bfr[n] = *(const bf16x8*)&lds_wf[((pos * 4 + n) * 64 + lane) * 8];
      #pragma unroll
      for (int mi = 0; mi < 4; ++mi) {
        if (!mvA[mi]) continue;
        int ny = oyA[mi] + ky, nx = oxA[mi] + kx;
        bool v = (jA[mi] < 196) & ((unsigned)ny < 14u) & ((unsigned)nx < 14u);
        int np = v ? (ny * 14 + nx) : 196;
        bf16x8 afr = *(const bf16x8*)&lds_in[np][lq * 8];
        acc[mi][0] = MFMA16(afr, bfr[0], acc[mi][0], 0, 0, 0);
        acc[mi][1] = MFMA16(afr, bfr[1], acc[mi][1], 0, 0, 0);
        acc[mi][2] = MFMA16(afr, bfr[2], acc[mi][2], 0, 0, 0);
        acc[mi][3] = MFMA16(afr, bfr[3], acc[mi][3], 0, 0, 0);
      }
    }
    __syncthreads();          // reads of stage p done -> lds_wf free for DMA
    if (p < 7) { WRITE_STAGE(p + 1); ISSUE_WDMA(p + 1); }
  }

  short* op = a_part + (size_t)src * FTQ;
  #pragma unroll
  for (int mi = 0; mi < 4; ++mi) {
    if (!mvA[mi]) continue;
    int mt = (mi < 3) ? (wave + mi * 4) : 12;
    #pragma unroll
    for (int n = 0; n < 4; ++n) {
      int oc = n * 16 + l15;
      #pragma unroll
      for (int r = 0; r < 4; ++r) {
        int j = mt * 16 + lq * 4 + r;
        if (j < NODES)
          op[((size_t)k * NODES + j) * 64 + oc] = f2bf(acc[mi][n][r]);
      }
    }
  }
#undef ISSUE_LOADS
#undef ISSUE_WDMA
#undef WRITE_STAGE
}

// ---------------- fused graph kernel (r13/r17: 2-slice combine, T14 prefetch, LDS-staged P7) ----------------
__global__ __launch_bounds__(1024, 1) void graph_kernel(
    const short* __restrict__ a_part, const float* __restrict__ ss_aff2,
    const short* __restrict__ wafrag,
    const float* __restrict__ aff_b, const short* __restrict__ g1wf,
    const float* __restrict__ g1b, const unsigned short* __restrict__ roif_bf,
    const short* __restrict__ g2wf, const float* __restrict__ g2b,
    const unsigned short* __restrict__ roi_sem, float* __restrict__ outp)
{
  __shared__ __align__(16) char smem[125840];
  const int tid = threadIdx.x, wave = tid >> 6, lane = tid & 63;
  const int l15 = lane & 15, lq = lane >> 4;
  const int k = blockIdx.x;

  char*  Ab   = smem;                       // [208][464 B] bf16 A^T; dead after P6 (P7: rst)
  short* wa   = (short*)(smem + 96512);
  short* yfr  = (short*)(smem + 96512);
  short* zsf  = (short*)(smem + 103680);
  float* dsl  = (float*)(smem + 123136);
  float* g1bl = (float*)(smem + 123968);
  float* g2bl = (float*)(smem + 124032);
  float* affb = (float*)(smem + 125056);

  const bool wv13 = (wave < 13);
  const int jr  = wave * 16 + l15;
  const int jrc = min(jr, 195);
  const i32x4 z4 = {};
  const unsigned short* rsmk = roi_sem + (size_t)k * 50176;

  bf16x8 af0 = {}, af1 = {};
  if (wv13) {
    float s0[8] = {0,0,0,0,0,0,0,0}, s1[8] = {0,0,0,0,0,0,0,0};
    #pragma unroll
    for (int sl = 0; sl < 2; ++sl) {
      const unsigned short* p = (const unsigned short*)a_part + (size_t)sl * FTQ
                                + ((size_t)k * NODES + jrc) * 64 + lq * 8;
      u16x8 v0 = *(const u16x8*)p;
      u16x8 v1 = *(const u16x8*)(p + 32);
      #pragma unroll
      for (int e = 0; e < 8; ++e) { s0[e] += bf2f(v0[e]); s1[e] += bf2f(v1[e]); }
    }
    #pragma unroll
    for (int e = 0; e < 8; ++e) {
      int oc0 = lq * 8 + e, oc1 = 32 + lq * 8 + e;
      af0[e] = f2bf(fmaxf(s0[e] * ss_aff2[oc0] + ss_aff2[64 + oc0], 0.f));
      af1[e] = f2bf(fmaxf(s1[e] * ss_aff2[oc1] + ss_aff2[64 + oc1], 0.f));
    }
  }
  {
    i32x4 w0 = ((const i32x4*)wafrag)[tid];
    i32x4 w1 = z4;
    if (tid < 640) w1 = ((const i32x4*)wafrag)[1024 + tid];
    if (tid < 832) {
      int r = tid >> 2, q = tid & 3;
      *(i32x4*)(Ab + r * 464 + 384 + q * 16) = z4;
    }
    if (tid < 196) affb[tid] = aff_b[tid];
    if (tid < 256) g2bl[tid] = g2b[tid];
    if (tid < 16)  g1bl[tid] = g1b[tid];
    ((i32x4*)wa)[tid] = w0;
    if (tid < 640) ((i32x4*)wa)[1024 + tid] = w1;
  }
  __syncthreads();

  if (wv13) {
    float rsum[4] = {0.f, 0.f, 0.f, 0.f};
    #pragma unroll
    for (int n = 0; n < 13; ++n) {
      bf16x8 b0 = *(const bf16x8*)(wa + (n * 64 + lane) * 8);
      bf16x8 b1 = *(const bf16x8*)(wa + ((13 + n) * 64 + lane) * 8);
      f32x4 acc = {0.f, 0.f, 0.f, 0.f};
      acc = MFMA16(af0, b0, acc, 0, 0, 0);
      acc = MFMA16(af1, b1, acc, 0, 0, 0);
      int i = n * 16 + l15;
      bool iv = (i < 196);
      float bv = affb[iv ? i : 0];
      #pragma unroll
      for (int r = 0; r < 4; ++r) {
        float v = acc[r] + bv;
        float s = 1.f / (1.f + __expf(-v));
        if (iv) {
          rsum[r] += s;
          *(short*)(Ab + (wave * 16 + lq * 4 + r) * 464 + i * 2) = f2bf(s);
        }
      }
    }
    #pragma unroll
    for (int r = 0; r < 4; ++r) {
      float v = rsum[r];
      v += __shfl_xor(v, 1); v += __shfl_xor(v, 2);
      v += __shfl_xor(v, 4); v += __shfl_xor(v, 8);
      int j = wave * 16 + lq * 4 + r;
      if (l15 == 0 && j < 196) dsl[j] = rsqrtf(v);
    }
  }
  __syncthreads();

  *(i32x4*)(smem + 96512 + tid * 16) = z4;
  if (tid < 256) *(i32x4*)(smem + 96512 + (1024 + tid) * 16) = z4;
  f32x4 xacc = {0.f, 0.f, 0.f, 0.f};
  if (wv13) {
    const unsigned short* Xp = roif_bf + (size_t)k * 50176 + (size_t)jrc * 256 + lq * 8;
    #pragma unroll
    for (int ks = 0; ks < 8; ++ks) {
      bf16x8 xa = *(const bf16x8*)(Xp + ks * 32);
      bf16x8 xb = *(const bf16x8*)(g1wf + (ks * 64 + lane) * 8);
      xacc = MFMA16(xa, xb, xacc, 0, 0, 0);
    }
  }
  __syncthreads();

  if (wv13) {
    #pragma unroll
    for (int r = 0; r < 4; ++r) {
      int i = wave * 16 + lq * 4 + r;
      if (i < 196) {
        float yv = dsl[i] * xacc[r];
        yfr[((i >> 5) * 64 + ((i >> 3) & 3) * 16 + l15) * 8 + (i & 7)] = f2bf(yv);
      }
    }
  }
  __syncthreads();

  f32x4 g0 = {0.f, 0.f, 0.f, 0.f};
  if (wv13) {
    #pragma unroll
    for (int ks = 0; ks < 7; ++ks) {
      bf16x8 bb = *(const bf16x8*)(yfr + (ks * 64 + lane) * 8);
      bf16x8 a0 = *(const bf16x8*)(Ab + jr * 464 + ks * 64 + lq * 16);
      g0 = MFMA16(a0, bb, g0, 0, 0, 0);
    }
  }
  __syncthreads();
  if (wv13) {
    #pragma unroll
    for (int r = 0; r < 4; ++r) {
      int i = wave * 16 + lq * 4 + r;
      if (i < 196) {
        float d = dsl[i];
        float x1v = fmaxf(g0[r] * d + g1bl[l15], 0.f);
        yfr[((i >> 5) * 64 + ((i >> 3) & 3) * 16 + l15) * 8 + (i & 7)] = f2bf(d * x1v);
      }
    }
  }
  __syncthreads();

  u16x8 pre0[3];
  #pragma unroll
  for (int it = 0; it < 3; ++it) {
    int v = tid + it * 1024;
    int row = v >> 5, cq = v & 31;
    pre0[it] = *(const u16x8*)(rsmk + (size_t)row * 256 + cq * 8);
  }

  if (wv13) {
    f32x4 z0 = {0.f, 0.f, 0.f, 0.f};
    #pragma unroll
    for (int ks = 0; ks < 7; ++ks) {
      bf16x8 bb = *(const bf16x8*)(yfr + (ks * 64 + lane) * 8);
      bf16x8 a0 = *(const bf16x8*)(Ab + jr * 464 + ks * 64 + lq * 16);
      z0 = MFMA16(a0, bb, z0, 0, 0, 0);
    }
    #pragma unroll
    for (int r = 0; r < 4; ++r) {
      int j = wave * 16 + lq * 4 + r;
      if (j < 196) {
        float zv = z0[r] * dsl[j];
        zsf[((j >> 4) * 64 + (l15 >> 3) * 16 + (j & 15)) * 8 + (l15 & 7)] = f2bf(zv);
      }
    }
  }
  __syncthreads();

  {
    bf16x8 wf = *(const bf16x8*)(g2wf + (wave * 64 + lane) * 8);
    float* op = outp + (size_t)k * 50176;
    unsigned short* rst = (unsigned short*)smem;
    const int c_ = wave * 16 + lq * 4;
    float gbv[4];
    #pragma unroll
    for (int r = 0; r < 4; ++r) gbv[r] = g2bl[c_ + r];
    #pragma unroll
    for (int it = 0; it < 3; ++it) {
      int v = tid + it * 1024;
      int row = v >> 5, cq = v & 31;
      *(u16x8*)&rst[row * 264 + cq * 8] = pre0[it];
    }
    __syncthreads();
    u16x8 pre1[4];
    #pragma unroll
    for (int it = 0; it < 4; ++it) {
      int v = tid + it * 1024;
      if (v < 3200) {
        int row = v >> 5, cq = v & 31;
        pre1[it] = *(const u16x8*)(rsmk + (size_t)(96 + row) * 256 + cq * 8);
      }
    }
    #pragma unroll
    for (int jt = 0; jt < 6; ++jt) {
      bf16x8 zb = *(const bf16x8*)(zsf + (jt * 64 + lane) * 8);
      f32x4 d = {0.f, 0.f, 0.f, 0.f};
      d = MFMA16(wf, zb, d, 0, 0, 0);
      int j = jt * 16 + l15;
      const unsigned short* rr = rst + j * 264 + c_;
      unsigned int p01 = *(const unsigned int*)rr;
      unsigned int p23 = *(const unsigned int*)(rr + 2);
      op[(size_t)(c_ + 0) * 196 + j] = d[0] + gbv[0] + bf2f((unsigned short)(p01 & 0xffff));
      op[(size_t)(c_ + 1) * 196 + j] = d[1] + gbv[1] + bf2f((unsigned short)(p01 >> 16));
      op[(size_t)(c_ + 2) * 196 + j] = d[2] + gbv[2] + bf2f((unsigned short)(p23 & 0xffff));
      op[(size_t)(c_ + 3) * 196 + j] = d[3] + gbv[3] + bf2f((unsigned short)(p23 >> 16));
    }
    __syncthreads();
    #pragma unroll
    for (int it = 0; it < 4; ++it) {
      int v = tid + it * 1024;
      if (v < 3200) {
        int row = v >> 5, cq = v & 31;
        *(u16x8*)&rst[row * 264 + cq * 8] = pre1[it];
      }
    }
    __syncthreads();
    #pragma unroll
    for (int jt = 6; jt < 13; ++jt) {
      bf16x8 zb = *(const bf16x8*)(zsf + (jt * 64 + lane) * 8);
      f32x4 d = {0.f, 0.f, 0.f, 0.f};
      d = MFMA16(wf, zb, d, 0, 0, 0);
      int j = jt * 16 + l15;
      if (j < 196) {
        const unsigned short* rr = rst + (j - 96) * 264 + c_;
        unsigned int p01 = *(const unsigned int*)rr;
        unsigned int p23 = *(const unsigned int*)(rr + 2);
        op[(size_t)(c_ + 0) * 196 + j] = d[0] + gbv[0] + bf2f((unsigned short)(p01 & 0xffff));
        op[(size_t)(c_ + 1) * 196 + j] = d[1] + gbv[1] + bf2f((unsigned short)(p01 >> 16));
        op[(size_t)(c_ + 2) * 196 + j] = d[2] + gbv[2] + bf2f((unsigned short)(p23 & 0xffff));
        op[(size_t)(c_ + 3) * 196 + j] = d[3] + gbv[3] + bf2f((unsigned short)(p23 >> 16));
      }
    }
  }
}

extern "C" void kernel_launch(void* const* d_in, const int* in_sizes, int n_in,
                              void* d_out, int out_size, void* d_ws, size_t ws_size,
                              hipStream_t stream) {
  const float* roi_feature = (const float*)d_in[0];
  const float* semantic    = (const float*)d_in[1];
  const float* boxes       = (const float*)d_in[2];
  const float* bn_sem_g = (const float*)d_in[3];
  const float* bn_sem_b = (const float*)d_in[4];
  const float* bn_sem_m = (const float*)d_in[5];
  const float* bn_sem_v = (const float*)d_in[6];
  const float* conv_sem_w = (const float*)d_in[7];
  const float* conv_sem_b = (const float*)d_in[8];
  const float* bn_fpn_g = (const float*)d_in[9];
  const float* bn_fpn_b = (const float*)d_in[10];
  const float* bn_fpn_m = (const float*)d_in[11];
  const float* bn_fpn_v = (const float*)d_in[12];
  const float* conv_fpn_w = (const float*)d_in[13];
  const float* conv_fpn_b = (const float*)d_in[14];
  const float* bn_aff_g = (const float*)d_in[15];
  const float* bn_aff_b = (const float*)d_in[16];
  const float* bn_aff_m = (const float*)d_in[17];
  const float* bn_aff_v = (const float*)d_in[18];
  const float* conv_aff_w = (const float*)d_in[19];
  const float* conv_aff_b = (const float*)d_in[20];
  const float* gcn1_w = (const float*)d_in[21];
  const float* gcn1_b = (const float*)d_in[22];
  const float* gcn2_w = (const float*)d_in[23];
  const float* gcn2_b = (const float*)d_in[24];

  const size_t FT = (size_t)KBOX * NODES * CCH;       // 12,845,056 elements
  unsigned short* ws16      = (unsigned short*)d_ws;
  unsigned short* semt_bf   = ws16;                    // FT shorts
  unsigned short* roif_bf   = semt_bf + FT;
  unsigned short* roi_sem_b = roif_bf + FT;
  short*          a_part    = (short*)(roi_sem_b + FT);          // 2*FTQ bf16
  float*          ss_sem    = (float*)(a_part + 2 * (size_t)FTQ); // 512
  float*          ss_fpn    = ss_sem + 512;                      // 512
  float*          ss_aff2   = ss_fpn + 512;                      // 128
  short*          wfrag     = (short*)(ss_aff2 + 128);           // 294,912
  short*          wafrag    = wfrag + 294912;                    // 13,312
  short*          g1wf      = wafrag + 13312;                    // 4,096
  short*          g2wf      = g1wf + 4096;                       // 8,192

  prep_kernel<<<256, 256, 0, stream>>>(
      bn_sem_g, bn_sem_b, bn_sem_m, bn_sem_v, conv_sem_w, conv_sem_b,
      bn_fpn_g, bn_fpn_b, bn_fpn_m, bn_fpn_v, conv_fpn_w, conv_fpn_b,
      bn_aff_g, bn_aff_b, bn_aff_m, bn_aff_v, conv_aff_w, gcn1_w, gcn2_w,
      ss_sem, ss_fpn, ss_aff2, wfrag, wafrag, g1wf, g2wf);

  transpose_bf16_kernel<<<4 * 4 * 256, 256, 0, stream>>>(roi_feature, roif_bf, 256, 196);
  transpose_bf16_kernel<<<4 * 196 * 4, 256, 0, stream>>>(semantic, semt_bf, 256, 12544);
  roi_align_kernel<<<KBOX * 14, 512, 0, stream>>>(semt_bf, boxes, roi_sem_b);
  conv_ab_kernel<<<KBOX * 2, 256, 0, stream>>>(roi_sem_b, roif_bf, ss_sem, ss_fpn, wfrag, a_part);
  graph_kernel<<<KBOX, 1024, 0, stream>>>(a_part, ss_aff2, wafrag, conv_aff_b, g1wf, gcn1_b,
                                          roif_bf, g2wf, gcn2_b, roi_sem_b, (float*)d_out);
}